// Round 5
// baseline (305.478 us; speedup 1.0000x reference)
//
#include <hip/hip_runtime.h>
#include <hip/hip_fp16.h>

namespace {

constexpr int kFeat = 32;
constexpr int kNA = 64;
constexpr int kNE = 32;
constexpr int kGridElems = kFeat * kNA * kNE;   // 65536
constexpr int kPoleElems = kFeat * 2;           // 64
constexpr int kCols = kNA * kNE;                // 2048 grid columns
constexpr int kColS = kCols;                    // pole-south column index
constexpr int kColN = kCols + 1;                // pole-north column index
constexpr int kTotCols = kCols + 2;             // 2050

constexpr float kPi  = 3.14159265358979323846f;
constexpr float kPi2 = 1.57079632679489661923f;
constexpr float kOmegaAz = 0.09817477042468103f;   // 2*pi/64
constexpr float kOmegaEl = 0.09519977738150889f;   // pi/33
constexpr float kInvOmegaAz = 10.18591635788130f;  // 64/(2*pi)
constexpr float kInvOmegaEl = 10.50422624406509f;  // 33/pi
constexpr float kInvSinAz = 10.20229703f;          // 1/sin(2*pi/64)
constexpr float kInvSinEl = 10.52010966f;          // 1/sin(pi/33)

// Prepass: grid [F][A][E] fp32 -> gt [A*E + 2][F] fp16 (a feature column is
// one contiguous 64B cache line); poles appended as columns 2048/2049.
__global__ __launch_bounds__(256) void transpose_grid_h(
    const float* __restrict__ g, const float* __restrict__ poles,
    __half* __restrict__ gt) {
  int idx = blockIdx.x * 256 + threadIdx.x;
  if (idx < kGridElems) {
    int f = idx >> 11;       // / (NA*NE)
    int ae = idx & 2047;     // a*NE + e
    gt[ae * kFeat + f] = __float2half(g[idx]);
  }
  if (idx < kPoleElems) {
    int f = idx >> 1;
    int p = idx & 1;
    gt[(kCols + p) * kFeat + f] = __float2half(poles[idx]);
  }
}

struct PointSetup {
  int col_bl, col_br, col_tl, col_tr;
  float a1, a2, b1, b2;
};

__device__ __forceinline__ PointSetup setup_point(float az, float el) {
  PointSetup s;
  // azimuth bucket: ar = smallest k with tick_az[k] >= az; ticks at -pi + k*omega
  float ta = (az + kPi) * kInvOmegaAz;
  int ar0 = (int)ceilf(ta);
  int al = ar0 - 1;
  int ar = (ar0 >= kNA) ? 0 : ar0;
  if (al < 0) al = kNA - 1;
  float theta_a = az - (-kPi + (float)al * kOmegaAz);
  float w1a = __sinf(kOmegaAz - theta_a) * kInvSinAz;
  float w2a = __sinf(theta_a) * kInvSinAz;

  // elevation: er = searchsorted(interior ticks at -pi/2 + (k+1)*omega_el)
  float ue = (el + kPi2) * kInvOmegaEl;
  int er = (int)ceilf(ue) - 1;
  er = min(max(er, 0), kNE);
  bool south = (er == 0);
  bool north = (er == kNE);
  int eil = min(max(er - 1, 0), kNE - 1);
  int eir = min(er, kNE - 1);
  float base = south ? -kPi2 : (-kPi2 + (float)(eil + 1) * kOmegaEl);
  float theta_e = el - base;
  float w1e = __sinf(kOmegaEl - theta_e) * kInvSinEl;
  float w2e = __sinf(theta_e) * kInvSinEl;

  s.col_bl = al * kNE + eil;
  s.col_br = ar * kNE + eil;
  s.col_tl = al * kNE + eir;
  s.col_tr = ar * kNE + eir;
  s.a1 = w1e * w1a; s.a2 = w1e * w2a;
  s.b1 = w2e * w1a; s.b2 = w2e * w2a;
  // Pole redirect: exact pole value via two identical half-weight columns
  // (NORMALIZED=False, weights need not sum to 1).
  if (south) {
    s.col_bl = kColS; s.col_br = kColS;
    s.a1 = 0.5f * w1e; s.a2 = s.a1;
  }
  if (north) {
    s.col_tl = kColN; s.col_tr = kColN;
    s.b1 = 0.5f * w2e; s.b2 = s.b1;
  }
  return s;
}

// Direct-store interp: thread = (feature-octet j, 4 consecutive points).
// No LDS, no barriers -- the R4 post-mortem says the barrier-bracketed
// compute/LDS/flush phases serialize per wave (sum-of-phases, not
// max-of-pipes). Here every wave runs gather->compute->store independently:
//  - gathers keep the proven shape: per instr, 16 points x one 16B half-quad
//    of one 64B column = 16 distinct whole 64B lines;
//  - stores are float4 spanning 4 points: per wave-store, 4 feature rows x
//    256B fully-written contiguous segments (128B-line complete -> no RFO,
//    16x fewer store instrs than the 64B-segment R0 scheme);
//  - pts loads are float4 (one 256B wave-read per array);
//  - the 4-point in-thread loop gives ILP to hide gather latency; no LDS
//    means occupancy is VGPR-limited only (~8 waves/SIMD).
__global__ __launch_bounds__(256) void interp_v(
    const float* __restrict__ pts, const __half* __restrict__ gt,
    float* __restrict__ out, int n) {
  const int t = threadIdx.x;
  const int j = t & 3;          // feature octet 8j..8j+7
  const int g = t >> 2;         // point-group within block (0..63)
  const int p0 = blockIdx.x * 256 + g * 4;
  if (p0 >= n) return;
  const size_t sn = (size_t)n;
  const bool full = (p0 + 4 <= n);

  float az[4], el[4];
  if (full) {
    float4 a4 = *(const float4*)(pts + p0);
    float4 e4 = *(const float4*)(pts + n + p0);
    az[0] = a4.x; az[1] = a4.y; az[2] = a4.z; az[3] = a4.w;
    el[0] = e4.x; el[1] = e4.y; el[2] = e4.z; el[3] = e4.w;
  } else {
#pragma unroll
    for (int k = 0; k < 4; ++k) {
      int p = p0 + k;
      if (p < n) { az[k] = pts[p]; el[k] = pts[n + p]; }
      else       { az[k] = 0.f;    el[k] = 0.f; }
    }
  }

  float acc[8][4];              // [row within octet][point]
  const int off = j * 8;
#pragma unroll
  for (int k = 0; k < 4; ++k) {
    PointSetup s = setup_point(az[k], el[k]);
    union H8 { uint4 u; __half2 h[4]; };
    H8 bl, br, tl, tr;
    bl.u = *(const uint4*)(gt + s.col_bl * kFeat + off);
    br.u = *(const uint4*)(gt + s.col_br * kFeat + off);
    tl.u = *(const uint4*)(gt + s.col_tl * kFeat + off);
    tr.u = *(const uint4*)(gt + s.col_tr * kFeat + off);
#pragma unroll
    for (int q = 0; q < 4; ++q) {
      float2 vbl = __half22float2(bl.h[q]);
      float2 vbr = __half22float2(br.h[q]);
      float2 vtl = __half22float2(tl.h[q]);
      float2 vtr = __half22float2(tr.h[q]);
      acc[2 * q + 0][k] = s.a1 * vbl.x + s.a2 * vbr.x + s.b1 * vtl.x + s.b2 * vtr.x;
      acc[2 * q + 1][k] = s.a1 * vbl.y + s.a2 * vbr.y + s.b1 * vtl.y + s.b2 * vtr.y;
    }
  }

  if (full) {
#pragma unroll
    for (int r = 0; r < 8; ++r) {
      float4 v = make_float4(acc[r][0], acc[r][1], acc[r][2], acc[r][3]);
      *(float4*)(out + (size_t)(8 * j + r) * sn + p0) = v;
    }
  } else {
#pragma unroll
    for (int r = 0; r < 8; ++r) {
      float* o = out + (size_t)(8 * j + r) * sn;
#pragma unroll
      for (int k = 0; k < 4; ++k)
        if (p0 + k < n) o[p0 + k] = acc[r][k];
    }
  }
}

// Fallback if the workspace is too small for the transposed fp16 grid:
// gather directly from the [F][A][E] layout (scalar strided loads).
__global__ __launch_bounds__(256) void interp_d(
    const float* __restrict__ pts, const float* __restrict__ g,
    const float* __restrict__ poles, float* __restrict__ out, int n) {
  int i = blockIdx.x * 256 + threadIdx.x;
  if (i >= n) return;
  float az = pts[i];
  float el = pts[n + i];
  PointSetup s = setup_point(az, el);

  float a1 = s.a1, a2 = s.a2, b1 = s.b1, b2 = s.b2;
  float pw0 = 0.0f, pw1 = 0.0f;
  if (s.col_bl == kColS) { pw0 = a1 + a2; a1 = 0.0f; a2 = 0.0f; }
  if (s.col_tl == kColN) { pw1 = b1 + b2; b1 = 0.0f; b2 = 0.0f; }

  const float* gbl = g + (s.col_bl < kCols ? s.col_bl : 0);
  const float* gbr = g + (s.col_br < kCols ? s.col_br : 0);
  const float* gtl = g + (s.col_tl < kCols ? s.col_tl : 0);
  const float* gtr = g + (s.col_tr < kCols ? s.col_tr : 0);
  size_t sn = (size_t)n;
#pragma unroll 8
  for (int f = 0; f < kFeat; ++f) {
    float v = a1 * gbl[f * kCols] + a2 * gbr[f * kCols]
            + b1 * gtl[f * kCols] + b2 * gtr[f * kCols]
            + pw0 * poles[f * 2 + 0] + pw1 * poles[f * 2 + 1];
    out[(size_t)f * sn + i] = v;
  }
}

}  // namespace

extern "C" void kernel_launch(void* const* d_in, const int* in_sizes, int n_in,
                              void* d_out, int out_size, void* d_ws, size_t ws_size,
                              hipStream_t stream) {
  (void)n_in; (void)out_size;
  const float* pts   = (const float*)d_in[0];
  const float* grid  = (const float*)d_in[1];
  const float* poles = (const float*)d_in[2];
  float* out = (float*)d_out;
  int n = in_sizes[0] / 2;

  size_t need = (size_t)(kTotCols * kFeat) * sizeof(__half);
  if (ws_size >= need) {
    __half* gt = (__half*)d_ws;
    transpose_grid_h<<<(kGridElems + 255) / 256, 256, 0, stream>>>(grid, poles, gt);
    int blocks = (n + 255) / 256;   // 256 points per 256-thread block
    interp_v<<<blocks, 256, 0, stream>>>(pts, gt, out, n);
  } else {
    int blocks = (n + 255) / 256;
    interp_d<<<blocks, 256, 0, stream>>>(pts, grid, poles, out, n);
  }
}

// Round 7
// 301.536 us; speedup vs baseline: 1.0131x; 1.0131x over previous
//
#include <hip/hip_runtime.h>
#include <hip/hip_fp16.h>

namespace {

constexpr int kFeat = 32;
constexpr int kNA = 64;
constexpr int kNE = 32;
constexpr int kGridElems = kFeat * kNA * kNE;   // 65536
constexpr int kPoleElems = kFeat * 2;           // 64
constexpr int kCols = kNA * kNE;                // 2048 grid columns
constexpr int kColS = kCols;                    // pole-south column index
constexpr int kColN = kCols + 1;                // pole-north column index
constexpr int kTotCols = kCols + 2;             // 2050

constexpr float kPi  = 3.14159265358979323846f;
constexpr float kPi2 = 1.57079632679489661923f;
constexpr float kOmegaAz = 0.09817477042468103f;   // 2*pi/64
constexpr float kOmegaEl = 0.09519977738150889f;   // pi/33
constexpr float kInvOmegaAz = 10.18591635788130f;  // 64/(2*pi)
constexpr float kInvOmegaEl = 10.50422624406509f;  // 33/pi
constexpr float kInvSinAz = 10.20229703f;          // 1/sin(2*pi/64)
constexpr float kInvSinEl = 10.52010966f;          // 1/sin(pi/33)

// native 4-float vector for nontemporal builtins (HIP's float4/uint4 are
// class types, which __builtin_nontemporal_store rejects)
typedef float vfloat4 __attribute__((ext_vector_type(4)));

// Prepass: grid [F][A][E] fp32 -> gt [A*E + 2][F] fp16 (a feature column is
// one contiguous 64B cache line); poles appended as columns 2048/2049.
__global__ __launch_bounds__(256) void transpose_grid_h(
    const float* __restrict__ g, const float* __restrict__ poles,
    __half* __restrict__ gt) {
  int idx = blockIdx.x * 256 + threadIdx.x;
  if (idx < kGridElems) {
    int f = idx >> 11;       // / (NA*NE)
    int ae = idx & 2047;     // a*NE + e
    gt[ae * kFeat + f] = __float2half(g[idx]);
  }
  if (idx < kPoleElems) {
    int f = idx >> 1;
    int p = idx & 1;
    gt[(kCols + p) * kFeat + f] = __float2half(poles[idx]);
  }
}

struct PointSetup {
  int col_bl, col_br, col_tl, col_tr;
  float a1, a2, b1, b2;
};

__device__ __forceinline__ PointSetup setup_point(float az, float el) {
  PointSetup s;
  // azimuth bucket: ar = smallest k with tick_az[k] >= az; ticks at -pi + k*omega
  float ta = (az + kPi) * kInvOmegaAz;
  int ar0 = (int)ceilf(ta);
  int al = ar0 - 1;
  int ar = (ar0 >= kNA) ? 0 : ar0;
  if (al < 0) al = kNA - 1;
  float theta_a = az - (-kPi + (float)al * kOmegaAz);
  float w1a = __sinf(kOmegaAz - theta_a) * kInvSinAz;
  float w2a = __sinf(theta_a) * kInvSinAz;

  // elevation: er = searchsorted(interior ticks at -pi/2 + (k+1)*omega_el)
  float ue = (el + kPi2) * kInvOmegaEl;
  int er = (int)ceilf(ue) - 1;
  er = min(max(er, 0), kNE);
  bool south = (er == 0);
  bool north = (er == kNE);
  int eil = min(max(er - 1, 0), kNE - 1);
  int eir = min(er, kNE - 1);
  float base = south ? -kPi2 : (-kPi2 + (float)(eil + 1) * kOmegaEl);
  float theta_e = el - base;
  float w1e = __sinf(kOmegaEl - theta_e) * kInvSinEl;
  float w2e = __sinf(theta_e) * kInvSinEl;

  s.col_bl = al * kNE + eil;
  s.col_br = ar * kNE + eil;
  s.col_tl = al * kNE + eir;
  s.col_tr = ar * kNE + eir;
  s.a1 = w1e * w1a; s.a2 = w1e * w2a;
  s.b1 = w2e * w1a; s.b2 = w2e * w2a;
  // Pole redirect: exact pole value via two identical half-weight columns
  // (NORMALIZED=False, weights need not sum to 1).
  if (south) {
    s.col_bl = kColS; s.col_br = kColS;
    s.a1 = 0.5f * w1e; s.a2 = s.a1;
  }
  if (north) {
    s.col_tl = kColN; s.col_tr = kColN;
    s.b1 = 0.5f * w2e; s.b2 = s.b1;
  }
  return s;
}

// R4 structure (champion) + two targeted fixes:
//  (a) NT flush stores: each wave-store writes 1 KB = 8 complete 128B L2
//      lines, so `nt` (evict-first) is line-split-safe here; it keeps the
//      256 MB write stream from evicting the 128 KB gather table out of L2
//      (R1's NT regression was on 64B half-line stores -- a confound).
//  (b) LDS column XOR-swizzle (col = p ^ (j<<3)): tile rows are 1 KB so every
//      row starts at bank 0; unswizzled, the 4 j-lanes of a point write the
//      same bank (4-way conflict, 1.58x). Swizzled: j-groups map to disjoint
//      bank halves -> uniform 2-way, which is free. Flush un-swizzles with
//      the same XOR (16B alignment and intra-uint4 point order preserved).
constexpr int kTile = 256;               // points per block
constexpr int kTileFloats = kFeat * kTile;   // 8192 floats = 32 KiB LDS

__global__ __launch_bounds__(256) void interp_t(
    const float* __restrict__ pts, const __half* __restrict__ gt,
    float* __restrict__ out, int n) {
  __shared__ float tile[kTileFloats];    // [feat][point-swizzled], row-major
  const int base = blockIdx.x * kTile;
  const int rem = min(kTile, n - base);
  const size_t sn = (size_t)n;
  const int t = threadIdx.x;

  // ---- compute phase: 4 local slots per thread (slots L = t, t+256, ...) ----
  int   pidx[4];
  float azv[4], elv[4];
#pragma unroll
  for (int c = 0; c < 4; ++c) {
    int L = t + 256 * c;
    int p = L >> 2;
    pidx[c] = p;
    if (p < rem) {
      int i = base + p;
      azv[c] = pts[i];
      elv[c] = pts[n + i];
    } else {
      azv[c] = 0.f; elv[c] = 0.f;
    }
  }

#pragma unroll
  for (int c = 0; c < 4; ++c) {
    int L = t + 256 * c;
    int p = pidx[c];
    int j = L & 3;
    if (p < rem) {
      PointSetup s = setup_point(azv[c], elv[c]);
      union H8 { uint4 u; __half2 h[4]; };
      H8 bl, br, tl, tr;
      const int off = j * 8;
      bl.u = *(const uint4*)(gt + s.col_bl * kFeat + off);
      br.u = *(const uint4*)(gt + s.col_br * kFeat + off);
      tl.u = *(const uint4*)(gt + s.col_tl * kFeat + off);
      tr.u = *(const uint4*)(gt + s.col_tr * kFeat + off);

      const int colw = p ^ (j << 3);               // bank swizzle
      float* dst = tile + (8 * j) * kTile + colw;  // rows 8j..8j+7
#pragma unroll
      for (int q = 0; q < 4; ++q) {
        float2 vbl = __half22float2(bl.h[q]);
        float2 vbr = __half22float2(br.h[q]);
        float2 vtl = __half22float2(tl.h[q]);
        float2 vtr = __half22float2(tr.h[q]);
        dst[(2 * q + 0) * kTile] =
            s.a1 * vbl.x + s.a2 * vbr.x + s.b1 * vtl.x + s.b2 * vtr.x;
        dst[(2 * q + 1) * kTile] =
            s.a1 * vbl.y + s.a2 * vbr.y + s.b1 * vtl.y + s.b2 * vtr.y;
      }
    }
  }

  __syncthreads();

  // ---- flush phase: LDS tile -> global, 1 KB contiguous per wave-store ----
  if (rem == kTile) {
#pragma unroll
    for (int r = 0; r < 8; ++r) {
      int u = t + 256 * r;
      int row = u >> 6;          // 64 lanes of a wave share one row
      int c4 = (u & 63) * 4;     // output point offset within tile
      int swz = c4 ^ ((row >> 3) << 3);
      vfloat4 v = *(const vfloat4*)(tile + row * kTile + swz);
      __builtin_nontemporal_store(
          v, (vfloat4*)(out + (size_t)row * sn + base + c4));
    }
  } else {
    // last partial tile: guarded element stores (un-swizzle per element)
    for (int r = 0; r < 8; ++r) {
      int u = t + 256 * r;
      int row = u >> 6;
      int c4 = (u & 63) * 4;
      int jrow = row >> 3;
      float* o = out + (size_t)row * sn + base;
      for (int e = 0; e < 4; ++e) {
        int p = c4 + e;
        if (p < rem) o[p] = tile[row * kTile + (p ^ (jrow << 3))];
      }
    }
  }
}

// Fallback if the workspace is too small for the transposed fp16 grid:
// gather directly from the [F][A][E] layout (scalar strided loads).
__global__ __launch_bounds__(256) void interp_d(
    const float* __restrict__ pts, const float* __restrict__ g,
    const float* __restrict__ poles, float* __restrict__ out, int n) {
  int i = blockIdx.x * 256 + threadIdx.x;
  if (i >= n) return;
  float az = pts[i];
  float el = pts[n + i];
  PointSetup s = setup_point(az, el);

  float a1 = s.a1, a2 = s.a2, b1 = s.b1, b2 = s.b2;
  float pw0 = 0.0f, pw1 = 0.0f;
  if (s.col_bl == kColS) { pw0 = a1 + a2; a1 = 0.0f; a2 = 0.0f; }
  if (s.col_tl == kColN) { pw1 = b1 + b2; b1 = 0.0f; b2 = 0.0f; }

  const float* gbl = g + (s.col_bl < kCols ? s.col_bl : 0);
  const float* gbr = g + (s.col_br < kCols ? s.col_br : 0);
  const float* gtl = g + (s.col_tl < kCols ? s.col_tl : 0);
  const float* gtr = g + (s.col_tr < kCols ? s.col_tr : 0);
  size_t sn = (size_t)n;
#pragma unroll 8
  for (int f = 0; f < kFeat; ++f) {
    float v = a1 * gbl[f * kCols] + a2 * gbr[f * kCols]
            + b1 * gtl[f * kCols] + b2 * gtr[f * kCols]
            + pw0 * poles[f * 2 + 0] + pw1 * poles[f * 2 + 1];
    out[(size_t)f * sn + i] = v;
  }
}

}  // namespace

extern "C" void kernel_launch(void* const* d_in, const int* in_sizes, int n_in,
                              void* d_out, int out_size, void* d_ws, size_t ws_size,
                              hipStream_t stream) {
  (void)n_in; (void)out_size;
  const float* pts   = (const float*)d_in[0];
  const float* grid  = (const float*)d_in[1];
  const float* poles = (const float*)d_in[2];
  float* out = (float*)d_out;
  int n = in_sizes[0] / 2;

  size_t need = (size_t)(kTotCols * kFeat) * sizeof(__half);
  if (ws_size >= need) {
    __half* gt = (__half*)d_ws;
    transpose_grid_h<<<(kGridElems + 255) / 256, 256, 0, stream>>>(grid, poles, gt);
    int blocks = (n + kTile - 1) / kTile;
    interp_t<<<blocks, 256, 0, stream>>>(pts, gt, out, n);
  } else {
    int blocks = (n + 255) / 256;
    interp_d<<<blocks, 256, 0, stream>>>(pts, grid, poles, out, n);
  }
}